// Round 2
// baseline (126.926 us; speedup 1.0000x reference)
//
#include <hip/hip_runtime.h>

typedef _Float16 half4 __attribute__((ext_vector_type(4)));
typedef float    f32x4 __attribute__((ext_vector_type(4)));

#define MFMA16(a,b,c) __builtin_amdgcn_mfma_f32_16x16x16f16((a),(b),(c),0,0,0)

static constexpr int N_NODES  = 200000;
static constexpr int N_GRAPHS = 64;
static constexpr int GPG      = 256;              // 16-node groups per graph (max 4096 nodes/graph; ~3125±55 expected)
static constexpr int TOTAL_G  = N_GRAPHS * GPG;   // 16384

// ---- workspace byte offsets ----
static constexpr size_t WS_ZWT    = 0;        // [64][128][16] f16 : (z@W1)^T per graph, d-major k-inner
static constexpr size_t WS_W2T    = 262144;   // [128][128] f16    : W2T[d_out][d_in]
static constexpr size_t WS_WHT    = 294912;   // [16][128]  f16    : rows 0..3 = [Wp|Wv]^T, rest zero
static constexpr size_t WS_GSTART = 299008;   // 65 int : first node of graph g (batch is sorted)

// ---------------- single prep kernel: gstart + W2T + WhT + zW1^T ----------------
__global__ __launch_bounds__(256) void gnn_prep(
    const int* __restrict__ batch,
    const float* __restrict__ z,
    const float* __restrict__ W1,
    const float* __restrict__ W2,
    const float* __restrict__ Wp,
    const float* __restrict__ Wv,
    int* __restrict__ gstart,
    _Float16* __restrict__ zwt,
    _Float16* __restrict__ w2t,
    _Float16* __restrict__ wht)
{
    const int b = blockIdx.x, t = threadIdx.x;
    if (b < 782) {
        // graph boundaries from sorted batch
        const int i = b * 256 + t;
        if (i < N_NODES) {
            const int bi   = batch[i];
            const int prev = (i == 0) ? -1 : batch[i - 1];
            if (bi != prev)
                for (int g = prev + 1; g <= bi; ++g) gstart[g] = i;
            if (i == N_NODES - 1)
                for (int g = bi + 1; g <= N_GRAPHS; ++g) gstart[g] = N_NODES;
        }
    } else if (b < 846) {
        // W2^T -> f16
        const int e = (b - 782) * 256 + t;    // 0..16383
        const int n = e >> 7, kk = e & 127;
        w2t[e] = (_Float16)W2[kk * 128 + n];
    } else if (b < 854) {
        // head weights [Wp|Wv]^T padded to 16 rows
        const int e = (b - 846) * 256 + t;    // 0..2047
        const int j = e >> 7, d = e & 127;
        float v = 0.f;
        if (j < 2)      v = Wp[d * 2 + j];
        else if (j < 4) v = Wv[d * 2 + (j - 2)];
        wht[e] = (_Float16)v;
    } else {
        // zwt[g][d][k] = sum_c z[g,k,c] * W1[c,d]; 2 (g,k) pairs per block, 8 waves/CU
        const int p = (b - 854) * 2 + (t >> 7);  // 0..1023
        const int g = p >> 4, k = p & 15, d = t & 127;
        const float* zr = z + (g * 16 + k) * 128;
        float a0 = 0.f, a1 = 0.f, a2 = 0.f, a3 = 0.f;
#pragma unroll 8
        for (int c = 0; c < 128; c += 4) {
            a0 += zr[c    ] * W1[(c    ) * 128 + d];   // W1 coalesced over d; zr scalar (uniform)
            a1 += zr[c + 1] * W1[(c + 1) * 128 + d];
            a2 += zr[c + 2] * W1[(c + 2) * 128 + d];
            a3 += zr[c + 3] * W1[(c + 3) * 128 + d];
        }
        zwt[(g * 128 + d) * 16 + k] = (_Float16)((a0 + a1) + (a2 + a3));
    }
}

__device__ inline float fast_tanh(float x) {
    x = fminf(fmaxf(x, -15.f), 15.f);
    const float e = __expf(2.f * x);
    return (e - 1.f) / (e + 1.f);
}

// ---------------- main: fused slot-sum + MLP + heads, zero LDS, register-chained ----------------
// All GEMMs transposed: lane&15 = node column everywhere; 16x16x16 C row-run (quad*4+i)
// == next MFMA's B k-run -> register pass-through between GEMMs.
__global__ __launch_bounds__(256, 2) void gnn_main(
    const float* __restrict__ s,
    const float* __restrict__ b1,
    const float* __restrict__ b2,
    const float* __restrict__ bp,
    const float* __restrict__ bv,
    const _Float16* __restrict__ zwt,
    const _Float16* __restrict__ w2t,
    const _Float16* __restrict__ wht,
    const int* __restrict__ gstart,
    float* __restrict__ out)
{
    const int lane = threadIdx.x & 63;
    const int n16  = lane & 15;
    const int quad = lane >> 4;
    const int wid  = blockIdx.x * 4 + (threadIdx.x >> 6);
    const int nw   = gridDim.x * 4;

    // persistent W2^T fragments: A2'[m=d_out][k=d_in]  (128 VGPR)
    half4 a2[8][8];
#pragma unroll
    for (int mt = 0; mt < 8; ++mt)
#pragma unroll
        for (int t = 0; t < 8; ++t)
            a2[mt][t] = *(const half4*)(w2t + (mt * 16 + n16) * 128 + t * 16 + quad * 4);

    // persistent head fragments: A3[m=j][k=d] (rows j>=4 zero)  (16 VGPR)
    half4 a3[8];
#pragma unroll
    for (int t = 0; t < 8; ++t)
        a3[t] = *(const half4*)(wht + n16 * 128 + t * 16 + quad * 4);

    const float bp0 = bp[0], bp1 = bp[1], bv0 = bv[0], bv1 = bv[1];

    for (int gi = wid; gi < TOTAL_G; gi += nw) {
        const int g    = gi >> 8;
        const int idx  = gi & 255;
        const int gs   = gstart[g];
        const int ge   = gstart[g + 1];
        const int base = gs + idx * 16;
        if (base >= ge) continue;                 // wave-uniform skip of empty groups

        const int node  = base + n16;
        const bool valid = node < ge;

        // B1' frag: s^T[k=slot][n=node], K=16 native
        half4 bs = {(_Float16)0.f, (_Float16)0.f, (_Float16)0.f, (_Float16)0.f};
        if (valid) {
            const f32x4 sv = *(const f32x4*)(s + node * 16 + quad * 4);
            bs[0] = (_Float16)sv[0]; bs[1] = (_Float16)sv[1];
            bs[2] = (_Float16)sv[2]; bs[3] = (_Float16)sv[3];
        }

        // GEMM1' + bias + relu, per-mt transient accumulator -> h1 B2' frags
        const _Float16* zg = zwt + g * 2048;
        half4 h1[8];
#pragma unroll
        for (int mt = 0; mt < 8; ++mt) {
            const half4 a1 = *(const half4*)(zg + (mt * 16 + n16) * 16 + quad * 4);
            const f32x4 zc = {0.f, 0.f, 0.f, 0.f};
            const f32x4 acc = MFMA16(a1, bs, zc);
            const f32x4 bb = *(const f32x4*)(b1 + mt * 16 + quad * 4);
#pragma unroll
            for (int i = 0; i < 4; ++i)
                h1[mt][i] = (_Float16)fmaxf(acc[i] + bb[i], 0.f);
        }

        // GEMM2' (64 MFMA) fused with head (8 MFMA); h2 transient
        f32x4 acc3 = {0.f, 0.f, 0.f, 0.f};
#pragma unroll
        for (int mo = 0; mo < 8; ++mo) {
            f32x4 acc2 = {0.f, 0.f, 0.f, 0.f};
#pragma unroll
            for (int t = 0; t < 8; ++t)
                acc2 = MFMA16(a2[mo][t], h1[t], acc2);
            const f32x4 bb = *(const f32x4*)(b2 + mo * 16 + quad * 4);
            half4 h2;
#pragma unroll
            for (int i = 0; i < 4; ++i)
                h2[i] = (_Float16)fmaxf(acc2[i] + bb[i], 0.f);
            acc3 = MFMA16(a3[mo], h2, acc3);
        }

        // head out: lane = node, quad0 regs = j0..3 -> one dwordx4 per node
        if (quad == 0 && valid) {
            f32x4 o;
            o[0] = fast_tanh(acc3[0] + bp0);
            o[1] = fast_tanh(acc3[1] + bp1);
            o[2] = acc3[2] + bv0;
            o[3] = acc3[3] + bv1;
            *(f32x4*)(out + node * 4) = o;
        }
    }
}

extern "C" void kernel_launch(void* const* d_in, const int* in_sizes, int n_in,
                              void* d_out, int out_size, void* d_ws, size_t ws_size,
                              hipStream_t stream)
{
    const float* z     = (const float*)d_in[0];
    const float* s     = (const float*)d_in[1];
    const int*   batch = (const int*)d_in[2];
    const float* W1    = (const float*)d_in[3];
    const float* b1    = (const float*)d_in[4];
    const float* W2    = (const float*)d_in[5];
    const float* b2    = (const float*)d_in[6];
    const float* Wp    = (const float*)d_in[7];
    const float* bp    = (const float*)d_in[8];
    const float* Wv    = (const float*)d_in[9];
    const float* bv    = (const float*)d_in[10];
    float* out = (float*)d_out;

    char* w = (char*)d_ws;
    _Float16* zwt = (_Float16*)(w + WS_ZWT);
    _Float16* w2t = (_Float16*)(w + WS_W2T);
    _Float16* wht = (_Float16*)(w + WS_WHT);
    int* gstart   = (int*)(w + WS_GSTART);

    hipLaunchKernelGGL(gnn_prep, dim3(1366), dim3(256), 0, stream,
                       batch, z, W1, W2, Wp, Wv, gstart, zwt, w2t, wht);
    hipLaunchKernelGGL(gnn_main, dim3(512), dim3(256), 0, stream,
                       s, b1, b2, bp, bv, zwt, w2t, wht, gstart, out);
}

// Round 3
// 113.731 us; speedup vs baseline: 1.1160x; 1.1160x over previous
//
#include <hip/hip_runtime.h>

typedef _Float16 half4 __attribute__((ext_vector_type(4)));
typedef _Float16 half8 __attribute__((ext_vector_type(8)));
typedef float    f32x4 __attribute__((ext_vector_type(4)));

#define MFMA16(a,b,c) __builtin_amdgcn_mfma_f32_16x16x16f16((a),(b),(c),0,0,0)

static constexpr int N_NODES  = 200000;
static constexpr int N_GRAPHS = 64;
static constexpr int SGPG     = 128;               // 32-node supergroups per graph (max 4096 nodes/graph)
static constexpr int TOTAL_SG = N_GRAPHS * SGPG;   // 8192

// ---- workspace byte offsets ----
static constexpr size_t WS_ZWT    = 0;        // [64][128][16] f16 : (z@W1)^T per graph, d-major k-inner
static constexpr size_t WS_W2T    = 262144;   // [128][128] f16    : W2T[d_out][d_in]
static constexpr size_t WS_WHT    = 294912;   // [16][128]  f16    : rows 0..3 = [Wp|Wv]^T, rest zero
static constexpr size_t WS_GSTART = 299008;   // 65 int

// ---- LDS layout (37,888 B/block -> 4 blocks/CU) ----
// a2 pairs : [8 mo][4 tp][64 lane] x 16B = 32768    (frag pair t=2tp,2tp+1 for lane)
// a3       : [8 t][64 lane] x 8B        =  4096
// b1       : 128 f32                    =   512
// b2       : 128 f32                    =   512

// ---------------- single prep kernel ----------------
__global__ __launch_bounds__(256) void gnn_prep(
    const int* __restrict__ batch,
    const float* __restrict__ z,
    const float* __restrict__ W1,
    const float* __restrict__ W2,
    const float* __restrict__ Wp,
    const float* __restrict__ Wv,
    int* __restrict__ gstart,
    _Float16* __restrict__ zwt,
    _Float16* __restrict__ w2t,
    _Float16* __restrict__ wht)
{
    const int b = blockIdx.x, t = threadIdx.x;
    if (b < 782) {
        const int i = b * 256 + t;
        if (i < N_NODES) {
            const int bi   = batch[i];
            const int prev = (i == 0) ? -1 : batch[i - 1];
            if (bi != prev)
                for (int g = prev + 1; g <= bi; ++g) gstart[g] = i;
            if (i == N_NODES - 1)
                for (int g = bi + 1; g <= N_GRAPHS; ++g) gstart[g] = N_NODES;
        }
    } else if (b < 846) {
        const int e = (b - 782) * 256 + t;
        const int n = e >> 7, kk = e & 127;
        w2t[e] = (_Float16)W2[kk * 128 + n];
    } else if (b < 854) {
        const int e = (b - 846) * 256 + t;
        const int j = e >> 7, d = e & 127;
        float v = 0.f;
        if (j < 2)      v = Wp[d * 2 + j];
        else if (j < 4) v = Wv[d * 2 + (j - 2)];
        wht[e] = (_Float16)v;
    } else {
        const int p = (b - 854) * 2 + (t >> 7);
        const int g = p >> 4, k = p & 15, d = t & 127;
        const float* zr = z + (g * 16 + k) * 128;
        float a0 = 0.f, a1 = 0.f, a2 = 0.f, a3 = 0.f;
#pragma unroll 8
        for (int c = 0; c < 128; c += 4) {
            a0 += zr[c    ] * W1[(c    ) * 128 + d];
            a1 += zr[c + 1] * W1[(c + 1) * 128 + d];
            a2 += zr[c + 2] * W1[(c + 2) * 128 + d];
            a3 += zr[c + 3] * W1[(c + 3) * 128 + d];
        }
        zwt[(g * 128 + d) * 16 + k] = (_Float16)((a0 + a1) + (a2 + a3));
    }
}

__device__ inline float fast_tanh(float x) {
    x = fminf(fmaxf(x, -15.f), 15.f);
    const float e = __expf(2.f * x);
    return (e - 1.f) / (e + 1.f);
}

// ---------------- main ----------------
__global__ __launch_bounds__(256, 4) void gnn_main(
    const float* __restrict__ s,
    const float* __restrict__ b1,
    const float* __restrict__ b2,
    const float* __restrict__ bp,
    const float* __restrict__ bv,
    const _Float16* __restrict__ zwt,
    const _Float16* __restrict__ w2t,
    const _Float16* __restrict__ wht,
    const int* __restrict__ gstart,
    float* __restrict__ out)
{
    __shared__ char lds[37888];
    half8* a2l = (half8*)lds;                 // [mo*4+tp][lane]
    half4* a3l = (half4*)(lds + 32768);       // [t][lane]
    float* b1l = (float*)(lds + 36864);
    float* b2l = (float*)(lds + 37376);

    const int tid  = threadIdx.x;
    const int lane = tid & 63;
    const int n16  = lane & 15;
    const int quad = lane >> 4;

    // ---- stage weights into LDS ----
#pragma unroll
    for (int r = 0; r < 8; ++r) {
        const int e  = r * 256 + tid;         // 0..2047
        const int mo = e >> 8, tp = (e >> 6) & 3, ll = e & 63;
        const int nn = ll & 15, qq = ll >> 4;
        const _Float16* srcp = w2t + (mo * 16 + nn) * 128 + tp * 32 + qq * 4;
        half8 v;
        *(half4*)&v     = *(const half4*)srcp;        // t = 2tp
        *((half4*)&v+1) = *(const half4*)(srcp + 16); // t = 2tp+1
        a2l[e] = v;
    }
    {
        const int e = tid;                    // 0..255 -> a3 first half; +256 second
#pragma unroll
        for (int r = 0; r < 2; ++r) {
            const int ee = r * 256 + e;       // 0..511 : [t][lane]
            const int tt = ee >> 6, ll = ee & 63;
            const int nn = ll & 15, qq = ll >> 4;
            a3l[ee] = *(const half4*)(wht + nn * 128 + tt * 16 + qq * 4);
        }
        if (tid < 128)      b1l[tid] = b1[tid];
        else                b2l[tid - 128] = b2[tid - 128];
    }
    __syncthreads();

    const float bp0 = bp[0], bp1 = bp[1], bv0 = bv[0], bv1 = bv[1];
    f32x4 c3init = {0.f, 0.f, 0.f, 0.f};
    if (quad == 0) { c3init[0] = bp0; c3init[1] = bp1; c3init[2] = bv0; c3init[3] = bv1; }

    const int wid = blockIdx.x * 4 + (tid >> 6);
    const int nw  = gridDim.x * 4;

    for (int sgi = wid; sgi < TOTAL_SG; sgi += nw) {
        const int g    = sgi >> 7;
        const int idx  = sgi & 127;
        const int gs   = gstart[g];
        const int ge   = gstart[g + 1];
        const int base = gs + idx * 32;
        if (base >= ge) continue;             // wave-uniform skip

        const int nodeA = base + n16;
        const int nodeB = base + 16 + n16;
        const bool vA = nodeA < ge;
        const bool vB = nodeB < ge;

        // s fragments (B-operand of GEMM1'), issued first
        half4 bsA = {(_Float16)0.f, (_Float16)0.f, (_Float16)0.f, (_Float16)0.f};
        half4 bsB = bsA;
        if (vA) {
            const f32x4 sv = *(const f32x4*)(s + nodeA * 16 + quad * 4);
            bsA[0] = (_Float16)sv[0]; bsA[1] = (_Float16)sv[1];
            bsA[2] = (_Float16)sv[2]; bsA[3] = (_Float16)sv[3];
        }
        if (vB) {
            const f32x4 sv = *(const f32x4*)(s + nodeB * 16 + quad * 4);
            bsB[0] = (_Float16)sv[0]; bsB[1] = (_Float16)sv[1];
            bsB[2] = (_Float16)sv[2]; bsB[3] = (_Float16)sv[3];
        }

        // GEMM1' + relu (bias via C-init); h1 frags feed GEMM2' directly
        const _Float16* zg = zwt + g * 2048;
        half4 h1a[8], h1b[8];
#pragma unroll
        for (int mt = 0; mt < 8; ++mt) {
            const half4 a1 = *(const half4*)(zg + (mt * 16 + n16) * 16 + quad * 4);
            const f32x4 cb = *(const f32x4*)(b1l + mt * 16 + quad * 4);   // LDS broadcast
            const f32x4 accA = MFMA16(a1, bsA, cb);
            const f32x4 accB = MFMA16(a1, bsB, cb);
#pragma unroll
            for (int i = 0; i < 4; ++i) {
                h1a[mt][i] = (_Float16)fmaxf(accA[i], 0.f);
                h1b[mt][i] = (_Float16)fmaxf(accB[i], 0.f);
            }
        }

        // GEMM2' + relu + head, weights from LDS (each frag-pair feeds 4 MFMAs)
        f32x4 acc3a = c3init, acc3b = c3init;
#pragma unroll
        for (int mo = 0; mo < 8; ++mo) {
            const f32x4 cb = *(const f32x4*)(b2l + mo * 16 + quad * 4);
            f32x4 a2a = cb, a2b = cb;
#pragma unroll
            for (int tp = 0; tp < 4; ++tp) {
                const half8 w = a2l[(mo * 4 + tp) * 64 + lane];
                const half4 wlo = {w[0], w[1], w[2], w[3]};
                const half4 whi = {w[4], w[5], w[6], w[7]};
                a2a = MFMA16(wlo, h1a[tp * 2], a2a);
                a2a = MFMA16(whi, h1a[tp * 2 + 1], a2a);
                a2b = MFMA16(wlo, h1b[tp * 2], a2b);
                a2b = MFMA16(whi, h1b[tp * 2 + 1], a2b);
            }
            half4 h2a, h2b;
#pragma unroll
            for (int i = 0; i < 4; ++i) {
                h2a[i] = (_Float16)fmaxf(a2a[i], 0.f);
                h2b[i] = (_Float16)fmaxf(a2b[i], 0.f);
            }
            const half4 w3 = a3l[mo * 64 + lane];
            acc3a = MFMA16(w3, h2a, acc3a);
            acc3b = MFMA16(w3, h2b, acc3b);
        }

        if (quad == 0) {
            if (vA) {
                f32x4 o;
                o[0] = fast_tanh(acc3a[0]); o[1] = fast_tanh(acc3a[1]);
                o[2] = acc3a[2];            o[3] = acc3a[3];
                *(f32x4*)(out + nodeA * 4) = o;
            }
            if (vB) {
                f32x4 o;
                o[0] = fast_tanh(acc3b[0]); o[1] = fast_tanh(acc3b[1]);
                o[2] = acc3b[2];            o[3] = acc3b[3];
                *(f32x4*)(out + nodeB * 4) = o;
            }
        }
    }
}

extern "C" void kernel_launch(void* const* d_in, const int* in_sizes, int n_in,
                              void* d_out, int out_size, void* d_ws, size_t ws_size,
                              hipStream_t stream)
{
    const float* z     = (const float*)d_in[0];
    const float* s     = (const float*)d_in[1];
    const int*   batch = (const int*)d_in[2];
    const float* W1    = (const float*)d_in[3];
    const float* b1    = (const float*)d_in[4];
    const float* W2    = (const float*)d_in[5];
    const float* b2    = (const float*)d_in[6];
    const float* Wp    = (const float*)d_in[7];
    const float* bp    = (const float*)d_in[8];
    const float* Wv    = (const float*)d_in[9];
    const float* bv    = (const float*)d_in[10];
    float* out = (float*)d_out;

    char* w = (char*)d_ws;
    _Float16* zwt = (_Float16*)(w + WS_ZWT);
    _Float16* w2t = (_Float16*)(w + WS_W2T);
    _Float16* wht = (_Float16*)(w + WS_WHT);
    int* gstart   = (int*)(w + WS_GSTART);

    hipLaunchKernelGGL(gnn_prep, dim3(1366), dim3(256), 0, stream,
                       batch, z, W1, W2, Wp, Wv, gstart, zwt, w2t, wht);
    hipLaunchKernelGGL(gnn_main, dim3(1024), dim3(256), 0, stream,
                       s, b1, b2, bp, bv, zwt, w2t, wht, gstart, out);
}